// Round 8
// baseline (36.025 us; speedup 1.0000x reference)
//
#include <hip/hip_runtime.h>

#define HW 16384      // 128*128
#define NCH 128       // channels
#define CCH 4         // channels per thread
#define LANG 256
#define NH 128
#define NOP 6

typedef float f4 __attribute__((ext_vector_type(4)));

// Per-batch coefficients in d_ws: coefs[b*12 + 0..5] = gamma[b,k]*wr[k],
// coefs[b*12 + 6..11] = beta[b,k]*wr[k]; coefs[48] = sum(wr); coefs[49] = br.
__global__ __launch_bounds__(256) void coef_kernel(
    const float* __restrict__ lang, const float* __restrict__ Ws,
    const float* __restrict__ bs, const float* __restrict__ Wg,
    const float* __restrict__ bg, const float* __restrict__ Wb,
    const float* __restrict__ bb, const float* __restrict__ Wr,
    const float* __restrict__ br, float* __restrict__ coefs) {
  const int b = blockIdx.x;
  const int tid = threadIdx.x;
  const int wave = tid >> 6, lane = tid & 63;
  __shared__ float actv[NH];

  const f4 lv = *(const f4*)(lang + b * LANG + lane * 4);

  #pragma unroll 8
  for (int m = 0; m < 32; ++m) {
    const int j = wave * 32 + m;
    const f4 wv = *(const f4*)(Ws + (size_t)j * LANG + lane * 4);
    float p = lv.x * wv.x + lv.y * wv.y + lv.z * wv.z + lv.w * wv.w;
    #pragma unroll
    for (int off = 32; off; off >>= 1) p += __shfl_xor(p, off);
    if (lane == 0) actv[j] = p + bs[j];
  }
  __syncthreads();

  const float a0 = actv[lane * 2], a1 = actv[lane * 2 + 1];
  #pragma unroll
  for (int r = 0; r < 3; ++r) {
    const int k = wave + 4 * r;              // 0..11
    const int kk = (k < NOP) ? k : k - NOP;  // row in Wg/Wb
    const float* W = ((k < NOP) ? Wg : Wb) + kk * NH;
    float p = a0 * W[lane * 2] + a1 * W[lane * 2 + 1];
    #pragma unroll
    for (int off = 32; off; off >>= 1) p += __shfl_xor(p, off);
    if (lane == 0) {
      const float bias = (k < NOP) ? bg[kk] : bb[kk];
      coefs[b * 12 + k] = (p + bias) * Wr[kk];
    }
  }
  if (b == 0 && tid == 0) {
    float s = 0.f;
    #pragma unroll
    for (int k = 0; k < NOP; ++k) s += Wr[k];
    coefs[48] = s;
    coefs[49] = br[0];
  }
}

// Streaming affine. 2048 blocks (8/CU). The asm "memory" barrier pins all
// 10 vector loads BEFORE it — the compiler cannot sink them to just-before-
// use (R4 evidence: VGPR_Count=32 proved it was doing exactly that), so all
// 10 issue back-to-back and their latency overlaps.
__global__ __launch_bounds__(256) void apply_kernel(
    const float* __restrict__ x, const float* __restrict__ sem,
    const float* __restrict__ coefs, float* __restrict__ out) {
  const int b = blockIdx.z;
  const int cbase = blockIdx.y * CCH;
  const int pix = (blockIdx.x * 256 + threadIdx.x) * 4;

  const size_t base = ((size_t)b * NCH + cbase) * HW + pix;
  const float* xb = x + base;
  const float* semb = sem + ((size_t)b * 8 + 2) * HW + pix;

  // ---- issue all loads (independent) ----
  f4 x0 = *(const f4*)(xb + 0 * HW);
  f4 x1 = *(const f4*)(xb + 1 * HW);
  f4 x2 = *(const f4*)(xb + 2 * HW);
  f4 x3 = *(const f4*)(xb + 3 * HW);
  f4 s0 = *(const f4*)(semb + 0 * HW);
  f4 s1 = *(const f4*)(semb + 1 * HW);
  f4 s2 = *(const f4*)(semb + 2 * HW);
  f4 s3 = *(const f4*)(semb + 3 * HW);
  f4 s4 = *(const f4*)(semb + 4 * HW);
  f4 s5 = *(const f4*)(semb + 5 * HW);

  // coefs are wave-uniform -> scalar loads (issued before the barrier too)
  const float* gk = coefs + b * 12;
  const float g0 = gk[0], g1 = gk[1], g2 = gk[2], g3 = gk[3], g4 = gk[4], g5 = gk[5];
  const float e0 = gk[6], e1 = gk[7], e2 = gk[8], e3 = gk[9], e4 = gk[10], e5 = gk[11];
  const float wrsum = coefs[48];
  const float brv = coefs[49];

  // pin: nothing above sinks below, nothing below hoists above
  asm volatile("" ::: "memory");

  f4 scale = {wrsum, wrsum, wrsum, wrsum};
  f4 shift = {brv, brv, brv, brv};
  scale += g0 * s0; shift += e0 * s0;
  scale += g1 * s1; shift += e1 * s1;
  scale += g2 * s2; shift += e2 * s2;
  scale += g3 * s3; shift += e3 * s3;
  scale += g4 * s4; shift += e4 * s4;
  scale += g5 * s5; shift += e5 * s5;

  float* ob = out + base;
  *(f4*)(ob + 0 * HW) = x0 * scale + shift;
  *(f4*)(ob + 1 * HW) = x1 * scale + shift;
  *(f4*)(ob + 2 * HW) = x2 * scale + shift;
  *(f4*)(ob + 3 * HW) = x3 * scale + shift;
}

extern "C" void kernel_launch(void* const* d_in, const int* in_sizes, int n_in,
                              void* d_out, int out_size, void* d_ws, size_t ws_size,
                              hipStream_t stream) {
  const float* x    = (const float*)d_in[0];
  const float* lang = (const float*)d_in[1];
  const float* sem  = (const float*)d_in[2];
  const float* Ws   = (const float*)d_in[3];
  const float* bs   = (const float*)d_in[4];
  const float* Wg   = (const float*)d_in[5];
  const float* bg   = (const float*)d_in[6];
  const float* Wb   = (const float*)d_in[7];
  const float* bb   = (const float*)d_in[8];
  const float* Wr   = (const float*)d_in[9];
  const float* br   = (const float*)d_in[10];
  float* out = (float*)d_out;
  float* coefs = (float*)d_ws;  // 50 floats

  coef_kernel<<<dim3(4), dim3(256), 0, stream>>>(lang, Ws, bs, Wg, bg, Wb, bb,
                                                 Wr, br, coefs);

  dim3 grid(HW / (256 * 4), NCH / CCH, 4);  // (16, 32, 4) = 2048 blocks
  apply_kernel<<<grid, dim3(256), 0, stream>>>(x, sem, coefs, out);
}

// Round 9
// 32.572 us; speedup vs baseline: 1.1060x; 1.1060x over previous
//
#include <hip/hip_runtime.h>

#define HW 16384      // 128*128
#define NCH 128       // channels
#define CCH 8         // channels per thread
#define LANG 256
#define NH 128
#define NOP 6

typedef float f4 __attribute__((ext_vector_type(4)));

// Single fused dispatch, 1024 blocks x 256 threads.
// All 15 vmem streams (lang + 8 x-tiles + 6 sem-tiles) are issued as named
// registers BEFORE an asm memory pin, so the compiler cannot sink them
// (R4 evidence: without the pin it allocates 32 VGPRs and serializes loads
// at ~1.3 TB/s). Their latency hides under the per-block coef GEMV
// (Ws = 131 KB, L2-resident). Then combine + 8 stores.
__global__ __launch_bounds__(256) void fused_kernel(
    const float* __restrict__ x, const float* __restrict__ lang,
    const float* __restrict__ sem,
    const float* __restrict__ Ws, const float* __restrict__ bs,
    const float* __restrict__ Wg, const float* __restrict__ bg,
    const float* __restrict__ Wb, const float* __restrict__ bb,
    const float* __restrict__ Wr, const float* __restrict__ br,
    float* __restrict__ out) {
  const int b = blockIdx.z;
  const int cbase = blockIdx.y * CCH;
  const int tid = threadIdx.x;
  const int wave = tid >> 6, lane = tid & 63;
  const int pix = (blockIdx.x * 256 + tid) * 4;

  __shared__ float actv[NH];
  __shared__ float cf[12];  // 0..5: gamma*wr, 6..11: beta*wr

  const size_t base = ((size_t)b * NCH + cbase) * HW + pix;
  const float* xb = x + base;
  const float* semb = sem + ((size_t)b * 8 + 2) * HW + pix;

  // ---- issue ALL loads up front (15 independent vmem ops) ----
  const f4 lv = *(const f4*)(lang + b * LANG + lane * 4);
  const f4 x0 = *(const f4*)(xb + 0 * HW);
  const f4 x1 = *(const f4*)(xb + 1 * HW);
  const f4 x2 = *(const f4*)(xb + 2 * HW);
  const f4 x3 = *(const f4*)(xb + 3 * HW);
  const f4 x4 = *(const f4*)(xb + 4 * HW);
  const f4 x5 = *(const f4*)(xb + 5 * HW);
  const f4 x6 = *(const f4*)(xb + 6 * HW);
  const f4 x7 = *(const f4*)(xb + 7 * HW);
  const f4 s0 = *(const f4*)(semb + 0 * HW);
  const f4 s1 = *(const f4*)(semb + 1 * HW);
  const f4 s2 = *(const f4*)(semb + 2 * HW);
  const f4 s3 = *(const f4*)(semb + 3 * HW);
  const f4 s4 = *(const f4*)(semb + 4 * HW);
  const f4 s5 = *(const f4*)(semb + 5 * HW);

  // pin: loads above cannot sink below this point
  asm volatile("" ::: "memory");

  // ---- coef GEMV stage 1: actv[j] = bs[j] + lang[b,:] . Ws[j,:] ----
  #pragma unroll 8
  for (int m = 0; m < 32; ++m) {
    const int j = wave * 32 + m;
    const f4 wv = *(const f4*)(Ws + (size_t)j * LANG + lane * 4);
    float p = lv.x * wv.x + lv.y * wv.y + lv.z * wv.z + lv.w * wv.w;
    #pragma unroll
    for (int off = 32; off; off >>= 1) p += __shfl_xor(p, off);
    if (lane == 0) actv[j] = p + bs[j];
  }
  __syncthreads();

  // ---- stage 2: 12 dots of length 128, 3 per wave ----
  const float a0 = actv[lane * 2], a1 = actv[lane * 2 + 1];
  #pragma unroll
  for (int r = 0; r < 3; ++r) {
    const int k = wave + 4 * r;              // 0..11
    const int kk = (k < NOP) ? k : k - NOP;  // row in Wg/Wb
    const float* W = ((k < NOP) ? Wg : Wb) + kk * NH;
    float p = a0 * W[lane * 2] + a1 * W[lane * 2 + 1];
    #pragma unroll
    for (int off = 32; off; off >>= 1) p += __shfl_xor(p, off);
    if (lane == 0) {
      const float bias = (k < NOP) ? bg[kk] : bb[kk];
      cf[k] = (p + bias) * Wr[kk];
    }
  }
  __syncthreads();

  // ---- combine (Wr/br scalar-cached, uniform) ----
  float wrsum = 0.f;
  #pragma unroll
  for (int k = 0; k < NOP; ++k) wrsum += Wr[k];
  const float brv = br[0];
  f4 scale = {wrsum, wrsum, wrsum, wrsum};
  f4 shift = {brv, brv, brv, brv};
  scale += cf[0] * s0; shift += cf[6]  * s0;
  scale += cf[1] * s1; shift += cf[7]  * s1;
  scale += cf[2] * s2; shift += cf[8]  * s2;
  scale += cf[3] * s3; shift += cf[9]  * s3;
  scale += cf[4] * s4; shift += cf[10] * s4;
  scale += cf[5] * s5; shift += cf[11] * s5;

  // ---- 8 stores ----
  float* ob = out + base;
  *(f4*)(ob + 0 * HW) = x0 * scale + shift;
  *(f4*)(ob + 1 * HW) = x1 * scale + shift;
  *(f4*)(ob + 2 * HW) = x2 * scale + shift;
  *(f4*)(ob + 3 * HW) = x3 * scale + shift;
  *(f4*)(ob + 4 * HW) = x4 * scale + shift;
  *(f4*)(ob + 5 * HW) = x5 * scale + shift;
  *(f4*)(ob + 6 * HW) = x6 * scale + shift;
  *(f4*)(ob + 7 * HW) = x7 * scale + shift;
}

extern "C" void kernel_launch(void* const* d_in, const int* in_sizes, int n_in,
                              void* d_out, int out_size, void* d_ws, size_t ws_size,
                              hipStream_t stream) {
  const float* x    = (const float*)d_in[0];
  const float* lang = (const float*)d_in[1];
  const float* sem  = (const float*)d_in[2];
  const float* Ws   = (const float*)d_in[3];
  const float* bs   = (const float*)d_in[4];
  const float* Wg   = (const float*)d_in[5];
  const float* bg   = (const float*)d_in[6];
  const float* Wb   = (const float*)d_in[7];
  const float* bb   = (const float*)d_in[8];
  const float* Wr   = (const float*)d_in[9];
  const float* br   = (const float*)d_in[10];
  float* out = (float*)d_out;

  dim3 grid(HW / (256 * 4), NCH / CCH, 4);  // (16, 16, 4) = 1024 blocks
  fused_kernel<<<grid, dim3(256), 0, stream>>>(x, lang, sem, Ws, bs, Wg, bg,
                                               Wb, bb, Wr, br, out);
}